// Round 7
// baseline (206.075 us; speedup 1.0000x reference)
//
#include <hip/hip_runtime.h>
#include <hip/hip_bf16.h>

// ============================================================================
// AdaptiveDiffusionConv: out[b,n,o,t] = relu( sum_{k,f} Theta[k,f,o] * rhs_k )
//   rhs0 = x, rhs1 = a^T x, rhs2 = a^T rhs1   (a = adj .* spatial_attention)
// (a@a)^T x = a^T (a^T x)  -> two [1024x1024]^T @ [1024x192] batched GEMMs.
//
// R7 = MEASUREMENT ROUND: exact R3 kernels (best known, 76.6us), but the
// GEMM pair is launched 5x (deterministic & idempotent) to expose the pair's
// cost via dur-delta: dur ~= 76.6 + 4*G_pair (+ ~8 launch gaps).
// ============================================================================

typedef __attribute__((ext_vector_type(8))) __bf16 bf16x8;
typedef __attribute__((ext_vector_type(4))) float  f32x4;
typedef __attribute__((ext_vector_type(8))) short  short8;

__device__ inline unsigned short f32_to_bf16(float f) {
    unsigned int u = __builtin_bit_cast(unsigned int, f);
    unsigned int r = u + 0x7FFFu + ((u >> 16) & 1u);   // RNE
    return (unsigned short)(r >> 16);
}
__device__ inline float bf16_to_f32(unsigned short u) {
    unsigned int x = ((unsigned int)u) << 16;
    return __builtin_bit_cast(float, x);
}

__device__ inline void gload_lds16(const void* gsrc, void* ldst) {
    __builtin_amdgcn_global_load_lds(
        (const __attribute__((address_space(1))) unsigned int*)gsrc,
        (__attribute__((address_space(3))) unsigned int*)ldst,
        16, 0, 0);
}

// ---------------------------------------------------------------------------
// prep_a: aT[b][n][m] = bf16(adj[m][n] * sa[b][m][n]); 32x32 LDS tile transpose
// ---------------------------------------------------------------------------
__global__ void prep_a(const float* __restrict__ sa, const float* __restrict__ adj,
                       unsigned short* __restrict__ aT)
{
    __shared__ float tile[32][33];
    const int b  = blockIdx.z;
    const int m0 = blockIdx.y * 32;
    const int n0 = blockIdx.x * 32;
    const int tid = threadIdx.x;
    const int c  = tid & 31;
    const int r4 = tid >> 5;          // 0..7
    const float* sab = sa + (size_t)b * 1024 * 1024;
#pragma unroll
    for (int i = 0; i < 4; i++) {
        int rr = r4 + i * 8;
        size_t idx = (size_t)(m0 + rr) * 1024 + (n0 + c);
        tile[rr][c] = adj[idx] * sab[idx];
    }
    __syncthreads();
    unsigned short* aTb = aT + (size_t)b * 1024 * 1024;
#pragma unroll
    for (int i = 0; i < 4; i++) {
        int rr = r4 + i * 8;          // n offset in output
        aTb[(size_t)(n0 + rr) * 1024 + (m0 + c)] = f32_to_bf16(tile[c][rr]);
    }
}

// ---------------------------------------------------------------------------
// prep_x: xT[b][j][m] = bf16(x[b][m][j]), j = f*12+t (192)
// ---------------------------------------------------------------------------
__global__ void prep_x(const float* __restrict__ x, unsigned short* __restrict__ xT)
{
    __shared__ float tile[32][33];
    const int b  = blockIdx.z;
    const int j0 = blockIdx.y * 32;
    const int m0 = blockIdx.x * 32;
    const int tid = threadIdx.x;
    const int c  = tid & 31;
    const int r4 = tid >> 5;
    const float* xb = x + (size_t)b * 1024 * 192;
#pragma unroll
    for (int i = 0; i < 4; i++) {
        int rr = r4 + i * 8;          // m
        tile[rr][c] = xb[(size_t)(m0 + rr) * 192 + (j0 + c)];
    }
    __syncthreads();
    unsigned short* xTb = xT + (size_t)b * 192 * 1024;
#pragma unroll
    for (int i = 0; i < 4; i++) {
        int rr = r4 + i * 8;          // j
        xTb[(size_t)(j0 + rr) * 1024 + (m0 + c)] = f32_to_bf16(tile[c][rr]);
    }
}

// ---------------------------------------------------------------------------
// gemm_tn: Cout[b][j][n] (bf16) = sum_m Aop[b][j][m] * Bop[b][n][m]
// tile 96j x 128n, BK=64, 4 waves (2x2), wave tile 48x64 (24 MFMA/step).
// 3 LDS buffers, raw s_barrier + counted vmcnt(10); stage issued 2 steps
// ahead, A prefetched 1 step ahead; loads NEVER drained to zero in the loop.
// grid (8 n, 2 j, 16 b) = 256 blocks.
// ---------------------------------------------------------------------------
__global__ __launch_bounds__(256, 1)
void gemm_tn(const unsigned short* __restrict__ Aop,
             const unsigned short* __restrict__ Bop,
             unsigned short* __restrict__ Cout)
{
    const int b  = blockIdx.z;
    const int j0 = blockIdx.y * 96;
    const int n0 = blockIdx.x * 128;
    const unsigned short* Ab = Aop + (size_t)b * 192 * 1024;
    const unsigned short* Bb = Bop + (size_t)b * 1024 * 1024;

    __shared__ unsigned short Blds[3][128 * 64];   // 3 x 16KB, linear

    const int tid  = threadIdx.x;
    const int lane = tid & 63;
    const int wave = tid >> 6;      // 0..3
    const int wj   = wave >> 1;     // 0..1
    const int wn   = wave & 1;      // 0..1
    const int lr   = lane & 15;
    const int lg   = lane >> 4;     // 0..3 (k-group)

    const int srow = lane >> 3;            // 0..7
    const int sg16 = (lane & 7) ^ srow;    // swizzled source 16B-group

    f32x4 acc[3][4];
#pragma unroll
    for (int i = 0; i < 3; i++)
#pragma unroll
        for (int j = 0; j < 4; j++) acc[i][j] = f32x4{0.f, 0.f, 0.f, 0.f};

    const unsigned short* Arow[3];
#pragma unroll
    for (int ri = 0; ri < 3; ri++)
        Arow[ri] = Ab + (size_t)(j0 + wj * 48 + ri * 16 + lr) * 1024 + lg * 8;

    bf16x8 Ac[2][3], An[2][3];

    // ---- prologue: stage tiles 0,1 ; load A(0). Queue: [s0:4][s1:4][A0:6]
#pragma unroll
    for (int i = 0; i < 4; i++) {
        int c = wave * 4 + i;
        gload_lds16(Bb + (size_t)(n0 + 8 * c + srow) * 1024 + 0 + sg16 * 8,
                    &Blds[0][c * 512]);
    }
#pragma unroll
    for (int i = 0; i < 4; i++) {
        int c = wave * 4 + i;
        gload_lds16(Bb + (size_t)(n0 + 8 * c + srow) * 1024 + 64 + sg16 * 8,
                    &Blds[1][c * 512]);
    }
#pragma unroll
    for (int h = 0; h < 2; h++)
#pragma unroll
        for (int ri = 0; ri < 3; ri++)
            Ac[h][ri] = __builtin_bit_cast(bf16x8,
                *reinterpret_cast<const short8*>(Arow[ri] + h * 32));
    __builtin_amdgcn_sched_barrier(0);
    asm volatile("s_waitcnt vmcnt(10)" ::: "memory");   // tile-0 staging landed
    __builtin_amdgcn_s_barrier();
    __builtin_amdgcn_sched_barrier(0);

#pragma unroll
    for (int t = 0; t < 16; ++t) {
        // ---- B fragments from swizzled LDS buf t%3
        const unsigned short* ldsB = &Blds[t % 3][0];
        bf16x8 Bfr[2][4];
#pragma unroll
        for (int h = 0; h < 2; h++)
#pragma unroll
            for (int ci = 0; ci < 4; ci++) {
                int row = wn * 64 + ci * 16 + lr;
                int sw  = (h * 4 + lg) ^ (lr & 7);
                Bfr[h][ci] = __builtin_bit_cast(bf16x8,
                    *reinterpret_cast<const short8*>(ldsB + row * 64 + sw * 8));
            }
        // ---- issue stage for tile t+2 (lands ~2 K-steps later)
        if (t < 14) {
#pragma unroll
            for (int i = 0; i < 4; i++) {
                int c = wave * 4 + i;
                gload_lds16(Bb + (size_t)(n0 + 8 * c + srow) * 1024 + (t + 2) * 64 + sg16 * 8,
                            &Blds[(t + 2) % 3][c * 512]);
            }
        }
        // ---- prefetch A for tile t+1
        if (t < 15) {
#pragma unroll
            for (int h = 0; h < 2; h++)
#pragma unroll
                for (int ri = 0; ri < 3; ri++)
                    An[h][ri] = __builtin_bit_cast(bf16x8,
                        *reinterpret_cast<const short8*>(Arow[ri] + (t + 1) * 64 + h * 32));
        }
        // ---- 24 MFMA (compiler's wait for Ac also retires stage(t+1),
        //      which was issued before A(t) -> in-order retirement)
#pragma unroll
        for (int h = 0; h < 2; h++)
#pragma unroll
            for (int ri = 0; ri < 3; ri++)
#pragma unroll
                for (int ci = 0; ci < 4; ci++)
                    acc[ri][ci] = __builtin_amdgcn_mfma_f32_16x16x32_bf16(
                        Ac[h][ri], Bfr[h][ci], acc[ri][ci], 0, 0, 0);
#pragma unroll
        for (int h = 0; h < 2; h++)
#pragma unroll
            for (int ri = 0; ri < 3; ri++)
                Ac[h][ri] = An[h][ri];     // SSA-folds under full unroll
        // steady state in flight: stage(t+2):4 + A(t+1):6 = 10
        asm volatile("s_waitcnt vmcnt(10)" ::: "memory");
        __builtin_amdgcn_s_barrier();
        __builtin_amdgcn_sched_barrier(0);
    }

    // ---- epilogue: D layout col = lane&15, row = (lane>>4)*4 + reg
    unsigned short* Cb = Cout + (size_t)b * 192 * 1024;
    const int jw = j0 + wj * 48;
    const int nw = n0 + wn * 64;
#pragma unroll
    for (int ri = 0; ri < 3; ri++)
#pragma unroll
        for (int ci = 0; ci < 4; ci++) {
            int col = nw + ci * 16 + lr;
#pragma unroll
            for (int r = 0; r < 4; r++) {
                int row = jw + ri * 16 + lg * 4 + r;
                Cb[(size_t)row * 1024 + col] = f32_to_bf16(acc[ri][ci][r]);
            }
        }
}

// ---------------------------------------------------------------------------
// final_contract: out[b,n,o,t] = relu( sum_f Th0[f,o]*xT + Th1[f,o]*r1 + Th2[f,o]*r2 )
// block = 192 threads (64 n x 3 tq), out tile staged in padded LDS,
// coalesced float4 copy-out. grid (16 n-chunks, 16 b).
// ---------------------------------------------------------------------------
#define OBUF_STRIDE 196   // 192 + 4 pad

__global__ __launch_bounds__(192)
void final_contract(const unsigned short* __restrict__ xT,
                    const unsigned short* __restrict__ r1,
                    const unsigned short* __restrict__ r2,
                    const float* __restrict__ Theta,   // [3][16][16]
                    float* __restrict__ out)           // [B][1024][16][12]
{
    __shared__ float th[768];
    __shared__ float obuf[64 * OBUF_STRIDE];

    const int tid = threadIdx.x;
    for (int i = tid; i < 768; i += 192) th[i] = Theta[i];
    __syncthreads();

    const int b  = blockIdx.y;
    const int n0 = blockIdx.x * 64;
    const int nl = tid & 63;
    const int tq = tid >> 6;          // 0..2

    float acc[4][16];
#pragma unroll
    for (int tt = 0; tt < 4; tt++)
#pragma unroll
        for (int o = 0; o < 16; o++) acc[tt][o] = 0.f;

    const size_t basep = (size_t)b * 192 * 1024 + n0 + nl;
#pragma unroll
    for (int f = 0; f < 16; f++) {
        size_t off = basep + (size_t)(f * 12 + tq * 4) * 1024;
        float v0[4], v1[4], v2[4];
#pragma unroll
        for (int tt = 0; tt < 4; tt++) {
            v0[tt] = bf16_to_f32(xT[off + (size_t)tt * 1024]);
            v1[tt] = bf16_to_f32(r1[off + (size_t)tt * 1024]);
            v2[tt] = bf16_to_f32(r2[off + (size_t)tt * 1024]);
        }
        const f32x4* t0 = reinterpret_cast<const f32x4*>(&th[0 * 256 + f * 16]);
        const f32x4* t1 = reinterpret_cast<const f32x4*>(&th[1 * 256 + f * 16]);
        const f32x4* t2 = reinterpret_cast<const f32x4*>(&th[2 * 256 + f * 16]);
#pragma unroll
        for (int q = 0; q < 4; q++) {
            f32x4 w0 = t0[q], w1 = t1[q], w2 = t2[q];
#pragma unroll
            for (int tt = 0; tt < 4; tt++)
#pragma unroll
                for (int e = 0; e < 4; e++)
                    acc[tt][q * 4 + e] += v0[tt] * w0[e] + v1[tt] * w1[e] + v2[tt] * w2[e];
        }
    }
#pragma unroll
    for (int o = 0; o < 16; o++) {
        f32x4 v;
#pragma unroll
        for (int tt = 0; tt < 4; tt++) v[tt] = fmaxf(acc[tt][o], 0.f);
        *reinterpret_cast<f32x4*>(&obuf[nl * OBUF_STRIDE + o * 12 + tq * 4]) = v;
    }
    __syncthreads();

    float* outp = out + ((size_t)b * 1024 + n0) * 192;
#pragma unroll
    for (int i = 0; i < 16; i++) {
        int v   = tid + i * 192;
        int row = v / 48;
        int c   = v - row * 48;
        *reinterpret_cast<f32x4*>(&outp[(size_t)v * 4]) =
            *reinterpret_cast<const f32x4*>(&obuf[row * OBUF_STRIDE + c * 4]);
    }
}

// ---------------------------------------------------------------------------
extern "C" void kernel_launch(void* const* d_in, const int* in_sizes, int n_in,
                              void* d_out, int out_size, void* d_ws, size_t ws_size,
                              hipStream_t stream)
{
    const float* x     = (const float*)d_in[0];   // [16][1024][16][12]
    const float* sa    = (const float*)d_in[1];   // [16][1024][1024]
    const float* adj   = (const float*)d_in[2];   // [1024][1024]
    const float* Theta = (const float*)d_in[3];   // [3][16][16]
    float* out = (float*)d_out;

    char* ws = (char*)d_ws;
    const size_t SZ_AT = (size_t)16 * 1024 * 1024 * 2;  // 32 MB
    const size_t SZ_XT = (size_t)16 * 192  * 1024 * 2;  //  6 MB
    unsigned short* aT = (unsigned short*)ws;
    unsigned short* xT = (unsigned short*)(ws + SZ_AT);
    unsigned short* r1 = (unsigned short*)(ws + SZ_AT + SZ_XT);
    unsigned short* r2 = (unsigned short*)(ws + SZ_AT + 2 * SZ_XT);

    prep_a<<<dim3(32, 32, 16), 256, 0, stream>>>(sa, adj, aT);
    prep_x<<<dim3(32, 6, 16), 256, 0, stream>>>(x, xT);
    // MEASUREMENT: GEMM pair x5 (idempotent, deterministic).
    // dur - 76.6 ~= 4 * G_pair (+ ~8 launch gaps)
    for (int rep = 0; rep < 5; rep++) {
        gemm_tn<<<dim3(8, 2, 16), 256, 0, stream>>>(xT, aT, r1);   // rhs1T
        gemm_tn<<<dim3(8, 2, 16), 256, 0, stream>>>(r1, aT, r2);   // rhs2T
    }
    final_contract<<<dim3(16, 16), 192, 0, stream>>>(xT, r1, r2, Theta, out);
}

// Round 8
// 94.216 us; speedup vs baseline: 2.1873x; 2.1873x over previous
//
#include <hip/hip_runtime.h>
#include <hip/hip_bf16.h>

// ============================================================================
// AdaptiveDiffusionConv: out[b,n,o,t] = relu( sum_{k,f} Theta[k,f,o] * rhs_k )
//   rhs0 = x, rhs1 = a^T x, rhs2 = a^T rhs1   (a = adj .* spatial_attention)
// (a@a)^T x = a^T (a^T x)  -> two [1024x1024]^T @ [1024x192] batched GEMMs.
//
// R8: GEMM geometry change (R7 measured the pair at ~32us = dominant):
//  - block tile 192x64 (full M): B-operand read ONCE per GEMM (was 2x)
//  - 512 threads = 8 waves (4j x 2n) -> 2 waves/SIMD latency overlap
//  - bijective XCD swizzle: XCD k <- batches {2k,2k+1} (A strips L2-local)
//  - same R3-verified 3-buffer counted-vmcnt pipeline (vmcnt(7) here)
// ============================================================================

typedef __attribute__((ext_vector_type(8))) __bf16 bf16x8;
typedef __attribute__((ext_vector_type(4))) float  f32x4;
typedef __attribute__((ext_vector_type(8))) short  short8;

__device__ inline unsigned short f32_to_bf16(float f) {
    unsigned int u = __builtin_bit_cast(unsigned int, f);
    unsigned int r = u + 0x7FFFu + ((u >> 16) & 1u);   // RNE
    return (unsigned short)(r >> 16);
}
__device__ inline float bf16_to_f32(unsigned short u) {
    unsigned int x = ((unsigned int)u) << 16;
    return __builtin_bit_cast(float, x);
}

__device__ inline void gload_lds16(const void* gsrc, void* ldst) {
    __builtin_amdgcn_global_load_lds(
        (const __attribute__((address_space(1))) unsigned int*)gsrc,
        (__attribute__((address_space(3))) unsigned int*)ldst,
        16, 0, 0);
}

// ---------------------------------------------------------------------------
// prep_a: aT[b][n][m] = bf16(adj[m][n] * sa[b][m][n]); 32x32 LDS tile transpose
// ---------------------------------------------------------------------------
__global__ void prep_a(const float* __restrict__ sa, const float* __restrict__ adj,
                       unsigned short* __restrict__ aT)
{
    __shared__ float tile[32][33];
    const int b  = blockIdx.z;
    const int m0 = blockIdx.y * 32;
    const int n0 = blockIdx.x * 32;
    const int tid = threadIdx.x;
    const int c  = tid & 31;
    const int r4 = tid >> 5;          // 0..7
    const float* sab = sa + (size_t)b * 1024 * 1024;
#pragma unroll
    for (int i = 0; i < 4; i++) {
        int rr = r4 + i * 8;
        size_t idx = (size_t)(m0 + rr) * 1024 + (n0 + c);
        tile[rr][c] = adj[idx] * sab[idx];
    }
    __syncthreads();
    unsigned short* aTb = aT + (size_t)b * 1024 * 1024;
#pragma unroll
    for (int i = 0; i < 4; i++) {
        int rr = r4 + i * 8;          // n offset in output
        aTb[(size_t)(n0 + rr) * 1024 + (m0 + c)] = f32_to_bf16(tile[c][rr]);
    }
}

// ---------------------------------------------------------------------------
// prep_x: xT[b][j][m] = bf16(x[b][m][j]), j = f*12+t (192)
// ---------------------------------------------------------------------------
__global__ void prep_x(const float* __restrict__ x, unsigned short* __restrict__ xT)
{
    __shared__ float tile[32][33];
    const int b  = blockIdx.z;
    const int j0 = blockIdx.y * 32;
    const int m0 = blockIdx.x * 32;
    const int tid = threadIdx.x;
    const int c  = tid & 31;
    const int r4 = tid >> 5;
    const float* xb = x + (size_t)b * 1024 * 192;
#pragma unroll
    for (int i = 0; i < 4; i++) {
        int rr = r4 + i * 8;          // m
        tile[rr][c] = xb[(size_t)(m0 + rr) * 192 + (j0 + c)];
    }
    __syncthreads();
    unsigned short* xTb = xT + (size_t)b * 192 * 1024;
#pragma unroll
    for (int i = 0; i < 4; i++) {
        int rr = r4 + i * 8;          // j
        xTb[(size_t)(j0 + rr) * 1024 + (m0 + c)] = f32_to_bf16(tile[c][rr]);
    }
}

// ---------------------------------------------------------------------------
// gemm_tn: Cout[b][j][n] (bf16) = sum_m Aop[b][j][m] * Bop[b][n][m]
// tile 192j x 64n (full M), BK=64, 8 waves (4j x 2n), wave tile 48x32
// (12 MFMA/step/wave). 3 LDS buffers (24KB), raw s_barrier + counted
// vmcnt(7); stage(t+2) 1 instr/wave, A(t+1) 6 loads/wave; never drained.
// grid (16 n, 16 b) = 256 blocks x 512 thr; bijective XCD swizzle.
// ---------------------------------------------------------------------------
__global__ __launch_bounds__(512, 1)
void gemm_tn(const unsigned short* __restrict__ Aop,
             const unsigned short* __restrict__ Bop,
             unsigned short* __restrict__ Cout)
{
    // XCD swizzle: hw maps linear id round-robin (lin%8 = XCD);
    // swz = (lin&7)*32 + (lin>>3) -> XCD k owns swz [32k,32k+32) = batches 2k,2k+1
    const int lin = blockIdx.x + 16 * blockIdx.y;
    const int swz = (lin & 7) * 32 + (lin >> 3);
    const int nb  = swz & 15;
    const int b   = swz >> 4;

    const int n0 = nb * 64;
    const unsigned short* Ab = Aop + (size_t)b * 192 * 1024;
    const unsigned short* Bb = Bop + (size_t)b * 1024 * 1024;

    __shared__ unsigned short Blds[3][64 * 64];   // 3 x 8KB, linear

    const int tid  = threadIdx.x;
    const int lane = tid & 63;
    const int wave = tid >> 6;      // 0..7
    const int wj   = wave >> 1;     // 0..3 -> 48j each
    const int wn   = wave & 1;      // 0..1 -> 32n each
    const int lr   = lane & 15;
    const int lg   = lane >> 4;     // 0..3 (k-group)

    // staging: chunk c = wave covers rows 8c..8c+7 (1KB); lane -> row
    // 8c+(lane>>3), dest slot lane&7; source 16B-group pre-swizzled
    const int srow = lane >> 3;            // 0..7
    const int sg16 = (lane & 7) ^ srow;    // swizzled source 16B-group

    f32x4 acc[3][2];
#pragma unroll
    for (int i = 0; i < 3; i++)
#pragma unroll
        for (int j = 0; j < 2; j++) acc[i][j] = f32x4{0.f, 0.f, 0.f, 0.f};

    const unsigned short* Arow[3];
#pragma unroll
    for (int ri = 0; ri < 3; ri++)
        Arow[ri] = Ab + (size_t)(wj * 48 + ri * 16 + lr) * 1024 + lg * 8;

    bf16x8 Ac[2][3], An[2][3];

    // ---- prologue: stage tiles 0,1 (1 instr each); load A(0):6.
    gload_lds16(Bb + (size_t)(n0 + 8 * wave + srow) * 1024 + 0 + sg16 * 8,
                &Blds[0][wave * 512]);
    gload_lds16(Bb + (size_t)(n0 + 8 * wave + srow) * 1024 + 64 + sg16 * 8,
                &Blds[1][wave * 512]);
#pragma unroll
    for (int h = 0; h < 2; h++)
#pragma unroll
        for (int ri = 0; ri < 3; ri++)
            Ac[h][ri] = __builtin_bit_cast(bf16x8,
                *reinterpret_cast<const short8*>(Arow[ri] + h * 32));
    __builtin_amdgcn_sched_barrier(0);
    asm volatile("s_waitcnt vmcnt(7)" ::: "memory");   // own stage(0) landed
    __builtin_amdgcn_s_barrier();                      // join: all waves landed
    __builtin_amdgcn_sched_barrier(0);

#pragma unroll
    for (int t = 0; t < 16; ++t) {
        // ---- B fragments (4x ds_read_b128) from swizzled LDS buf t%3
        const unsigned short* ldsB = &Blds[t % 3][0];
        bf16x8 Bfr[2][2];
#pragma unroll
        for (int h = 0; h < 2; h++)
#pragma unroll
            for (int ci = 0; ci < 2; ci++) {
                int row = wn * 32 + ci * 16 + lr;
                int sw  = (h * 4 + lg) ^ (lr & 7);
                Bfr[h][ci] = __builtin_bit_cast(bf16x8,
                    *reinterpret_cast<const short8*>(ldsB + row * 64 + sw * 8));
            }
        // ---- issue stage for tile t+2 (1 gload_lds/wave)
        if (t < 14) {
            gload_lds16(Bb + (size_t)(n0 + 8 * wave + srow) * 1024 + (t + 2) * 64 + sg16 * 8,
                        &Blds[(t + 2) % 3][wave * 512]);
        }
        // ---- prefetch A for tile t+1 (6 loads/wave)
        if (t < 15) {
#pragma unroll
            for (int h = 0; h < 2; h++)
#pragma unroll
                for (int ri = 0; ri < 3; ri++)
                    An[h][ri] = __builtin_bit_cast(bf16x8,
                        *reinterpret_cast<const short8*>(Arow[ri] + (t + 1) * 64 + h * 32));
        }
        // ---- 12 MFMA (compiler's wait for Ac(t) also retires stage(t+1),
        //      issued earlier -> in-order retirement keeps the queue live)
#pragma unroll
        for (int h = 0; h < 2; h++)
#pragma unroll
            for (int ri = 0; ri < 3; ri++)
#pragma unroll
                for (int ci = 0; ci < 2; ci++)
                    acc[ri][ci] = __builtin_amdgcn_mfma_f32_16x16x32_bf16(
                        Ac[h][ri], Bfr[h][ci], acc[ri][ci], 0, 0, 0);
#pragma unroll
        for (int h = 0; h < 2; h++)
#pragma unroll
            for (int ri = 0; ri < 3; ri++)
                Ac[h][ri] = An[h][ri];     // SSA-folds under full unroll
        // steady state in flight: stage(t+2):1 + A(t+1):6 = 7
        asm volatile("s_waitcnt vmcnt(7)" ::: "memory");
        __builtin_amdgcn_s_barrier();
        __builtin_amdgcn_sched_barrier(0);
    }

    // ---- epilogue: D layout col = lane&15, row = (lane>>4)*4 + reg
    unsigned short* Cb = Cout + (size_t)b * 192 * 1024;
    const int jw = wj * 48;
    const int nw = n0 + wn * 32;
#pragma unroll
    for (int ri = 0; ri < 3; ri++)
#pragma unroll
        for (int ci = 0; ci < 2; ci++) {
            int col = nw + ci * 16 + lr;
#pragma unroll
            for (int r = 0; r < 4; r++) {
                int row = jw + ri * 16 + lg * 4 + r;
                Cb[(size_t)row * 1024 + col] = f32_to_bf16(acc[ri][ci][r]);
            }
        }
}

// ---------------------------------------------------------------------------
// final_contract: out[b,n,o,t] = relu( sum_f Th0[f,o]*xT + Th1[f,o]*r1 + Th2[f,o]*r2 )
// block = 192 threads (64 n x 3 tq), out tile staged in padded LDS,
// coalesced float4 copy-out. grid (16 n-chunks, 16 b).
// ---------------------------------------------------------------------------
#define OBUF_STRIDE 196   // 192 + 4 pad

__global__ __launch_bounds__(192)
void final_contract(const unsigned short* __restrict__ xT,
                    const unsigned short* __restrict__ r1,
                    const unsigned short* __restrict__ r2,
                    const float* __restrict__ Theta,   // [3][16][16]
                    float* __restrict__ out)           // [B][1024][16][12]
{
    __shared__ float th[768];
    __shared__ float obuf[64 * OBUF_STRIDE];

    const int tid = threadIdx.x;
    for (int i = tid; i < 768; i += 192) th[i] = Theta[i];
    __syncthreads();

    const int b  = blockIdx.y;
    const int n0 = blockIdx.x * 64;
    const int nl = tid & 63;
    const int tq = tid >> 6;          // 0..2

    float acc[4][16];
#pragma unroll
    for (int tt = 0; tt < 4; tt++)
#pragma unroll
        for (int o = 0; o < 16; o++) acc[tt][o] = 0.f;

    const size_t basep = (size_t)b * 192 * 1024 + n0 + nl;
#pragma unroll
    for (int f = 0; f < 16; f++) {
        size_t off = basep + (size_t)(f * 12 + tq * 4) * 1024;
        float v0[4], v1[4], v2[4];
#pragma unroll
        for (int tt = 0; tt < 4; tt++) {
            v0[tt] = bf16_to_f32(xT[off + (size_t)tt * 1024]);
            v1[tt] = bf16_to_f32(r1[off + (size_t)tt * 1024]);
            v2[tt] = bf16_to_f32(r2[off + (size_t)tt * 1024]);
        }
        const f32x4* t0 = reinterpret_cast<const f32x4*>(&th[0 * 256 + f * 16]);
        const f32x4* t1 = reinterpret_cast<const f32x4*>(&th[1 * 256 + f * 16]);
        const f32x4* t2 = reinterpret_cast<const f32x4*>(&th[2 * 256 + f * 16]);
#pragma unroll
        for (int q = 0; q < 4; q++) {
            f32x4 w0 = t0[q], w1 = t1[q], w2 = t2[q];
#pragma unroll
            for (int tt = 0; tt < 4; tt++)
#pragma unroll
                for (int e = 0; e < 4; e++)
                    acc[tt][q * 4 + e] += v0[tt] * w0[e] + v1[tt] * w1[e] + v2[tt] * w2[e];
        }
    }
#pragma unroll
    for (int o = 0; o < 16; o++) {
        f32x4 v;
#pragma unroll
        for (int tt = 0; tt < 4; tt++) v[tt] = fmaxf(acc[tt][o], 0.f);
        *reinterpret_cast<f32x4*>(&obuf[nl * OBUF_STRIDE + o * 12 + tq * 4]) = v;
    }
    __syncthreads();

    float* outp = out + ((size_t)b * 1024 + n0) * 192;
#pragma unroll
    for (int i = 0; i < 16; i++) {
        int v   = tid + i * 192;
        int row = v / 48;
        int c   = v - row * 48;
        *reinterpret_cast<f32x4*>(&outp[(size_t)v * 4]) =
            *reinterpret_cast<const f32x4*>(&obuf[row * OBUF_STRIDE + c * 4]);
    }
}

// ---------------------------------------------------------------------------
extern "C" void kernel_launch(void* const* d_in, const int* in_sizes, int n_in,
                              void* d_out, int out_size, void* d_ws, size_t ws_size,
                              hipStream_t stream)
{
    const float* x     = (const float*)d_in[0];   // [16][1024][16][12]
    const float* sa    = (const float*)d_in[1];   // [16][1024][1024]
    const float* adj   = (const float*)d_in[2];   // [1024][1024]
    const float* Theta = (const float*)d_in[3];   // [3][16][16]
    float* out = (float*)d_out;

    char* ws = (char*)d_ws;
    const size_t SZ_AT = (size_t)16 * 1024 * 1024 * 2;  // 32 MB
    const size_t SZ_XT = (size_t)16 * 192  * 1024 * 2;  //  6 MB
    unsigned short* aT = (unsigned short*)ws;
    unsigned short* xT = (unsigned short*)(ws + SZ_AT);
    unsigned short* r1 = (unsigned short*)(ws + SZ_AT + SZ_XT);
    unsigned short* r2 = (unsigned short*)(ws + SZ_AT + 2 * SZ_XT);

    prep_a<<<dim3(32, 32, 16), 256, 0, stream>>>(sa, adj, aT);
    prep_x<<<dim3(32, 6, 16), 256, 0, stream>>>(x, xT);
    gemm_tn<<<dim3(16, 16), 512, 0, stream>>>(xT, aT, r1);   // rhs1T
    gemm_tn<<<dim3(16, 16), 512, 0, stream>>>(r1, aT, r2);   // rhs2T
    final_contract<<<dim3(16, 16), 192, 0, stream>>>(xT, r1, r2, Theta, out);
}

// Round 9
// 79.601 us; speedup vs baseline: 2.5889x; 1.1836x over previous
//
#include <hip/hip_runtime.h>
#include <hip/hip_bf16.h>

// ============================================================================
// AdaptiveDiffusionConv: out[b,n,o,t] = relu( sum_{k,f} Theta[k,f,o] * rhs_k )
//   rhs0 = x, rhs1 = a^T x, rhs2 = a^T rhs1   (a = adj .* spatial_attention)
// (a@a)^T x = a^T (a^T x)  -> two [1024x1024]^T @ [1024x192] batched GEMMs.
//
// R9: geometry fixed at 96x128/256 blocks (R5/R8 showed BN=64 loses).
// Fix the measured per-step latency stall (R7: pair=32us, ~2400cyc/step):
//  - 5 LDS buffers, stage 4 steps ahead, A prefetched 2 ahead; issue order
//    [A(t+2)] before [stage(t+4)] so the compiler's implicit vmcnt wait for
//    A(t) forces only stages >=3 steps old (true ~810cyc B lead, no drain).
//  - bijective XCD swizzle: XCD k <- batches {2k,2k+1} (B 4MB = L2-resident,
//    2nd j-block read hits L2; A strips L2-local).
// prep/final kernels unchanged (measured near their HBM floors).
// ============================================================================

typedef __attribute__((ext_vector_type(8))) __bf16 bf16x8;
typedef __attribute__((ext_vector_type(4))) float  f32x4;
typedef __attribute__((ext_vector_type(8))) short  short8;

__device__ inline unsigned short f32_to_bf16(float f) {
    unsigned int u = __builtin_bit_cast(unsigned int, f);
    unsigned int r = u + 0x7FFFu + ((u >> 16) & 1u);   // RNE
    return (unsigned short)(r >> 16);
}
__device__ inline float bf16_to_f32(unsigned short u) {
    unsigned int x = ((unsigned int)u) << 16;
    return __builtin_bit_cast(float, x);
}

__device__ inline void gload_lds16(const void* gsrc, void* ldst) {
    __builtin_amdgcn_global_load_lds(
        (const __attribute__((address_space(1))) unsigned int*)gsrc,
        (__attribute__((address_space(3))) unsigned int*)ldst,
        16, 0, 0);
}

// ---------------------------------------------------------------------------
// prep_a: aT[b][n][m] = bf16(adj[m][n] * sa[b][m][n]); 32x32 LDS tile transpose
// ---------------------------------------------------------------------------
__global__ void prep_a(const float* __restrict__ sa, const float* __restrict__ adj,
                       unsigned short* __restrict__ aT)
{
    __shared__ float tile[32][33];
    const int b  = blockIdx.z;
    const int m0 = blockIdx.y * 32;
    const int n0 = blockIdx.x * 32;
    const int tid = threadIdx.x;
    const int c  = tid & 31;
    const int r4 = tid >> 5;          // 0..7
    const float* sab = sa + (size_t)b * 1024 * 1024;
#pragma unroll
    for (int i = 0; i < 4; i++) {
        int rr = r4 + i * 8;
        size_t idx = (size_t)(m0 + rr) * 1024 + (n0 + c);
        tile[rr][c] = adj[idx] * sab[idx];
    }
    __syncthreads();
    unsigned short* aTb = aT + (size_t)b * 1024 * 1024;
#pragma unroll
    for (int i = 0; i < 4; i++) {
        int rr = r4 + i * 8;          // n offset in output
        aTb[(size_t)(n0 + rr) * 1024 + (m0 + c)] = f32_to_bf16(tile[c][rr]);
    }
}

// ---------------------------------------------------------------------------
// prep_x: xT[b][j][m] = bf16(x[b][m][j]), j = f*12+t (192)
// ---------------------------------------------------------------------------
__global__ void prep_x(const float* __restrict__ x, unsigned short* __restrict__ xT)
{
    __shared__ float tile[32][33];
    const int b  = blockIdx.z;
    const int j0 = blockIdx.y * 32;
    const int m0 = blockIdx.x * 32;
    const int tid = threadIdx.x;
    const int c  = tid & 31;
    const int r4 = tid >> 5;
    const float* xb = x + (size_t)b * 1024 * 192;
#pragma unroll
    for (int i = 0; i < 4; i++) {
        int rr = r4 + i * 8;          // m
        tile[rr][c] = xb[(size_t)(m0 + rr) * 192 + (j0 + c)];
    }
    __syncthreads();
    unsigned short* xTb = xT + (size_t)b * 192 * 1024;
#pragma unroll
    for (int i = 0; i < 4; i++) {
        int rr = r4 + i * 8;          // j
        xTb[(size_t)(j0 + rr) * 1024 + (m0 + c)] = f32_to_bf16(tile[c][rr]);
    }
}

// ---------------------------------------------------------------------------
// gemm_tn: Cout[b][j][n] (bf16) = sum_m Aop[b][j][m] * Bop[b][n][m]
// tile 96j x 128n, BK=64, 4 waves (2x2), wave tile 48x64 (24 MFMA/step).
// 5 LDS buffers (80KB): stage 4 ahead, A 2 ahead; per-step order
// [ds_read][A(t+2)][SB][stage(t+4)][MFMA][s_barrier]. The compiler's
// implicit vmcnt for A(t) retires s(t+1) (issued 3 steps prior) -- loads
// never drained, ~810cyc B lead. grid (8n,2j,16b)=256, XCD-swizzled.
// ---------------------------------------------------------------------------
__global__ __launch_bounds__(256, 1)
void gemm_tn(const unsigned short* __restrict__ Aop,
             const unsigned short* __restrict__ Bop,
             unsigned short* __restrict__ Cout)
{
    // bijective XCD swizzle: hw XCD = lin%8; XCD k owns swz in [32k,32k+32)
    // = batches {2k,2k+1} (all nb,jb) -> B footprint 4MB = one L2.
    const int lin = blockIdx.x + 8 * (blockIdx.y + 2 * blockIdx.z);
    const int swz = (lin & 7) * 32 + (lin >> 3);
    const int nb  = swz & 7;
    const int jb  = (swz >> 3) & 1;
    const int b   = swz >> 4;

    const int j0 = jb * 96;
    const int n0 = nb * 128;
    const unsigned short* Ab = Aop + (size_t)b * 192 * 1024;
    const unsigned short* Bb = Bop + (size_t)b * 1024 * 1024;

    __shared__ unsigned short Blds[5][128 * 64];   // 5 x 16KB, linear

    const int tid  = threadIdx.x;
    const int lane = tid & 63;
    const int wave = tid >> 6;      // 0..3
    const int wj   = wave >> 1;     // 0..1
    const int wn   = wave & 1;      // 0..1
    const int lr   = lane & 15;
    const int lg   = lane >> 4;     // 0..3 (k-group)

    const int srow = lane >> 3;            // 0..7
    const int sg16 = (lane & 7) ^ srow;    // swizzled source 16B-group

    f32x4 acc[3][4];
#pragma unroll
    for (int i = 0; i < 3; i++)
#pragma unroll
        for (int j = 0; j < 4; j++) acc[i][j] = f32x4{0.f, 0.f, 0.f, 0.f};

    const unsigned short* Arow[3];
#pragma unroll
    for (int ri = 0; ri < 3; ri++)
        Arow[ri] = Ab + (size_t)(j0 + wj * 48 + ri * 16 + lr) * 1024 + lg * 8;

    bf16x8 Ac[2][3], An[2][3], Ann[2][3];

#define STAGE_TILE(T) \
    { _Pragma("unroll") \
      for (int i_ = 0; i_ < 4; i_++) { \
          int c_ = wave * 4 + i_; \
          gload_lds16(Bb + (size_t)(n0 + 8 * c_ + srow) * 1024 + (T) * 64 + sg16 * 8, \
                      &Blds[(T) % 5][c_ * 512]); \
      } }
#define LOAD_A(DST, T) \
    { _Pragma("unroll") \
      for (int h_ = 0; h_ < 2; h_++) \
          _Pragma("unroll") \
          for (int ri_ = 0; ri_ < 3; ri_++) \
              DST[h_][ri_] = __builtin_bit_cast(bf16x8, \
                  *reinterpret_cast<const short8*>(Arow[ri_] + (T) * 64 + h_ * 32)); }

    // ---- prologue (issue order matters for in-order vmcnt retirement):
    // s0 s1 s2 A0 s3 A1  (28 loads) -> wait s0 landed: vmcnt(24)
    STAGE_TILE(0)
    STAGE_TILE(1)
    STAGE_TILE(2)
    LOAD_A(Ac, 0)
    STAGE_TILE(3)
    LOAD_A(An, 1)
    __builtin_amdgcn_sched_barrier(0);
    asm volatile("s_waitcnt vmcnt(24)" ::: "memory");
    __builtin_amdgcn_s_barrier();
    __builtin_amdgcn_sched_barrier(0);

#pragma unroll
    for (int t = 0; t < 16; ++t) {
        // ---- B fragments (8x ds_read_b128) from swizzled buf t%5
        const unsigned short* ldsB = &Blds[t % 5][0];
        bf16x8 Bfr[2][4];
#pragma unroll
        for (int h = 0; h < 2; h++)
#pragma unroll
            for (int ci = 0; ci < 4; ci++) {
                int row = wn * 64 + ci * 16 + lr;
                int sw  = (h * 4 + lg) ^ (lr & 7);
                Bfr[h][ci] = __builtin_bit_cast(bf16x8,
                    *reinterpret_cast<const short8*>(ldsB + row * 64 + sw * 8));
            }
        // ---- A(t+2) prefetch FIRST (so A(t)-wait retires only old stages)
        if (t < 14) LOAD_A(Ann, t + 2)
        __builtin_amdgcn_sched_barrier(0);
        // ---- stage(t+4) AFTER the A loads
        if (t < 12) STAGE_TILE(t + 4)
        // ---- 24 MFMA; compiler emits vmcnt wait for Ac=A(t) -> retires
        //      s(t+1) (issued 3 steps ago) and nothing newer.
#pragma unroll
        for (int h = 0; h < 2; h++)
#pragma unroll
            for (int ri = 0; ri < 3; ri++)
#pragma unroll
                for (int ci = 0; ci < 4; ci++)
                    acc[ri][ci] = __builtin_amdgcn_mfma_f32_16x16x32_bf16(
                        Ac[h][ri], Bfr[h][ci], acc[ri][ci], 0, 0, 0);
#pragma unroll
        for (int h = 0; h < 2; h++)
#pragma unroll
            for (int ri = 0; ri < 3; ri++) {
                Ac[h][ri] = An[h][ri];     // SSA-folds under full unroll
                An[h][ri] = Ann[h][ri];
            }
        __builtin_amdgcn_s_barrier();
        __builtin_amdgcn_sched_barrier(0);
    }

    // ---- epilogue: D layout col = lane&15, row = (lane>>4)*4 + reg
    unsigned short* Cb = Cout + (size_t)b * 192 * 1024;
    const int jw = j0 + wj * 48;
    const int nw = n0 + wn * 64;
#pragma unroll
    for (int ri = 0; ri < 3; ri++)
#pragma unroll
        for (int ci = 0; ci < 4; ci++) {
            int col = nw + ci * 16 + lr;
#pragma unroll
            for (int r = 0; r < 4; r++) {
                int row = jw + ri * 16 + lg * 4 + r;
                Cb[(size_t)row * 1024 + col] = f32_to_bf16(acc[ri][ci][r]);
            }
        }
#undef STAGE_TILE
#undef LOAD_A
}

// ---------------------------------------------------------------------------
// final_contract: out[b,n,o,t] = relu( sum_f Th0[f,o]*xT + Th1[f,o]*r1 + Th2[f,o]*r2 )
// block = 192 threads (64 n x 3 tq), out tile staged in padded LDS,
// coalesced float4 copy-out. grid (16 n-chunks, 16 b).
// ---------------------------------------------------------------------------
#define OBUF_STRIDE 196   // 192 + 4 pad

__global__ __launch_bounds__(192)
void final_contract(const unsigned short* __restrict__ xT,
                    const unsigned short* __restrict__ r1,
                    const unsigned short* __restrict__ r2,
                    const float* __restrict__ Theta,   // [3][16][16]
                    float* __restrict__ out)           // [B][1024][16][12]
{
    __shared__ float th[768];
    __shared__ float obuf[64 * OBUF_STRIDE];

    const int tid = threadIdx.x;
    for (int i = tid; i < 768; i += 192) th[i] = Theta[i];
    __syncthreads();

    const int b  = blockIdx.y;
    const int n0 = blockIdx.x * 64;
    const int nl = tid & 63;
    const int tq = tid >> 6;          // 0..2

    float acc[4][16];
#pragma unroll
    for (int tt = 0; tt < 4; tt++)
#pragma unroll
        for (int o = 0; o < 16; o++) acc[tt][o] = 0.f;

    const size_t basep = (size_t)b * 192 * 1024 + n0 + nl;
#pragma unroll
    for (int f = 0; f < 16; f++) {
        size_t off = basep + (size_t)(f * 12 + tq * 4) * 1024;
        float v0[4], v1[4], v2[4];
#pragma unroll
        for (int tt = 0; tt < 4; tt++) {
            v0[tt] = bf16_to_f32(xT[off + (size_t)tt * 1024]);
            v1[tt] = bf16_to_f32(r1[off + (size_t)tt * 1024]);
            v2[tt] = bf16_to_f32(r2[off + (size_t)tt * 1024]);
        }
        const f32x4* t0 = reinterpret_cast<const f32x4*>(&th[0 * 256 + f * 16]);
        const f32x4* t1 = reinterpret_cast<const f32x4*>(&th[1 * 256 + f * 16]);
        const f32x4* t2 = reinterpret_cast<const f32x4*>(&th[2 * 256 + f * 16]);
#pragma unroll
        for (int q = 0; q < 4; q++) {
            f32x4 w0 = t0[q], w1 = t1[q], w2 = t2[q];
#pragma unroll
            for (int tt = 0; tt < 4; tt++)
#pragma unroll
                for (int e = 0; e < 4; e++)
                    acc[tt][q * 4 + e] += v0[tt] * w0[e] + v1[tt] * w1[e] + v2[tt] * w2[e];
        }
    }
#pragma unroll
    for (int o = 0; o < 16; o++) {
        f32x4 v;
#pragma unroll
        for (int tt = 0; tt < 4; tt++) v[tt] = fmaxf(acc[tt][o], 0.f);
        *reinterpret_cast<f32x4*>(&obuf[nl * OBUF_STRIDE + o * 12 + tq * 4]) = v;
    }
    __syncthreads();

    float* outp = out + ((size_t)b * 1024 + n0) * 192;
#pragma unroll
    for (int i = 0; i < 16; i++) {
        int v   = tid + i * 192;
        int row = v / 48;
        int c   = v - row * 48;
        *reinterpret_cast<f32x4*>(&outp[(size_t)v * 4]) =
            *reinterpret_cast<const f32x4*>(&obuf[row * OBUF_STRIDE + c * 4]);
    }
}

// ---------------------------------------------------------------------------
extern "C" void kernel_launch(void* const* d_in, const int* in_sizes, int n_in,
                              void* d_out, int out_size, void* d_ws, size_t ws_size,
                              hipStream_t stream)
{
    const float* x     = (const float*)d_in[0];   // [16][1024][16][12]
    const float* sa    = (const float*)d_in[1];   // [16][1024][1024]
    const float* adj   = (const float*)d_in[2];   // [1024][1024]
    const float* Theta = (const float*)d_in[3];   // [3][16][16]
    float* out = (float*)d_out;

    char* ws = (char*)d_ws;
    const size_t SZ_AT = (size_t)16 * 1024 * 1024 * 2;  // 32 MB
    const size_t SZ_XT = (size_t)16 * 192  * 1024 * 2;  //  6 MB
    unsigned short* aT = (unsigned short*)ws;
    unsigned short* xT = (unsigned short*)(ws + SZ_AT);
    unsigned short* r1 = (unsigned short*)(ws + SZ_AT + SZ_XT);
    unsigned short* r2 = (unsigned short*)(ws + SZ_AT + 2 * SZ_XT);

    prep_a<<<dim3(32, 32, 16), 256, 0, stream>>>(sa, adj, aT);
    prep_x<<<dim3(32, 6, 16), 256, 0, stream>>>(x, xT);
    gemm_tn<<<dim3(8, 2, 16), 256, 0, stream>>>(xT, aT, r1);   // rhs1T
    gemm_tn<<<dim3(8, 2, 16), 256, 0, stream>>>(r1, aT, r2);   // rhs2T
    final_contract<<<dim3(16, 16), 192, 0, stream>>>(xT, r1, r2, Theta, out);
}